// Round 2
// baseline (325.584 us; speedup 1.0000x reference)
//
#include <hip/hip_runtime.h>
#include <math.h>

#define COL 14
#define NJ 23
#define BATCH 4096
#define NJOINT (BATCH * NJ)              // 94208
#define RADIUS 4
#define THREADS 256
#define BLOCKS 1472                      // 5888 waves; 94208/5888 = 16 joints/wave EXACTLY
#define WAVES_TOTAL (BLOCKS * (THREADS / 64))
#define JPW (NJOINT / WAVES_TOTAL)       // 16
#define PAIRS (JPW / 2)                  // 8 iterations x 2 joints

__global__ __launch_bounds__(THREADS) void msq3d_kernel(
    const float* __restrict__ o,
    const float* __restrict__ h,
    const float* __restrict__ t,
    const int*   __restrict__ v,
    float* __restrict__ out)
{
    __shared__ float sM[COL * COL];         // M[row*COL + col]
    __shared__ float sColMin[COL], sColMax[COL];
    __shared__ float sWaveSum[THREADS / 64];

    const int tid = threadIdx.x;

    // ---- build Gaussian matrix M once per block (matches scipy reflect) ----
    // (byte-identical to the harness-verified version: absmax == 0.0)
    if (tid < COL * COL) {
        double wd[2 * RADIUS + 1];
        double wsum = 0.0;
        #pragma unroll
        for (int k = 0; k <= 2 * RADIUS; ++k) {
            double xx = (double)(k - RADIUS);
            wd[k] = exp(-0.5 * xx * xx);
            wsum += wd[k];
        }
        const int outr = tid / COL, ic = tid % COL;
        float acc = 0.0f;
        #pragma unroll
        for (int k = -RADIUS; k <= RADIUS; ++k) {
            int ii = (outr + k) % (2 * COL);
            if (ii < 0) ii += 2 * COL;
            if (ii >= COL) ii = 2 * COL - 1 - ii;
            if (ii == ic) acc += (float)(wd[k + RADIUS] / wsum);
        }
        sM[outr * COL + ic] = acc;
    }
    __syncthreads();
    if (tid < COL) {
        float mn = sM[tid], mx = mn;
        for (int r = 1; r < COL; ++r) {
            float x = sM[r * COL + tid];
            mn = fminf(mn, x);
            mx = fmaxf(mx, x);
        }
        sColMin[tid] = mn;
        sColMax[tid] = mx;
    }
    __syncthreads();

    const int lane = tid & 63;
    const int wave_in_blk = tid >> 6;
    const int gwave = blockIdx.x * (THREADS / 64) + wave_in_blk;
    const float scale = 1.0f / (float)COL;
    const int W = WAVES_TOTAL;

    // per-lane static geometry: lane handles elements q0..q0+3 of each 196-elem map
    const bool act = (lane < 49);           // 49 * 4 = 196
    const int q0 = lane * 4;
    int rk[4], ck[4];
    #pragma unroll
    for (int k = 0; k < 4; ++k) {
        int q = q0 + k;
        if (q > COL * COL - 1) q = COL * COL - 1;
        rk[k] = q / COL;
        ck[k] = q - rk[k] * COL;
    }

    float accD = 0.0f;   // d1 partial on all lanes; d2 folded in on lanes 0..2

    // ---- prologue: load pair 0 (jA = gwave, jB = gwave + W) ----
    int jA = gwave;
    int jB = gwave + W;
    float4 hA = make_float4(0.f, 0.f, 0.f, 0.f);
    float4 hB = make_float4(0.f, 0.f, 0.f, 0.f);
    if (act) {
        hA = ((const float4*)(h + (size_t)jA * (COL * COL)))[lane];
        hB = ((const float4*)(h + (size_t)jB * (COL * COL)))[lane];
    }
    float tA0 = t[jA * 3 + 0], tA1 = t[jA * 3 + 1], tA2 = t[jA * 3 + 2];
    float tB0 = t[jB * 3 + 0], tB1 = t[jB * 3 + 1], tB2 = t[jB * 3 + 2];
    int   vA0 = v[jA * 2 + 0];
    int   vB0 = v[jB * 2 + 0];

    // deferred d2 state (o-load result consumed one iteration later)
    float povA = 0.f, pcA = 0.f, povB = 0.f, pcB = 0.f;

    #pragma unroll 1
    for (int p = 0; p < PAIRS; ++p) {
        // ---- issue next pair's h/t/v loads before touching this pair ----
        float4 nA = make_float4(0.f, 0.f, 0.f, 0.f);
        float4 nB = make_float4(0.f, 0.f, 0.f, 0.f);
        float ntA0 = 0.f, ntA1 = 0.f, ntA2 = 0.f;
        float ntB0 = 0.f, ntB1 = 0.f, ntB2 = 0.f;
        int   nvA0 = 0, nvB0 = 0;
        if (p + 1 < PAIRS) {
            const int njA = jA + 2 * W;
            const int njB = jB + 2 * W;
            if (act) {
                nA = ((const float4*)(h + (size_t)njA * (COL * COL)))[lane];
                nB = ((const float4*)(h + (size_t)njB * (COL * COL)))[lane];
            }
            ntA0 = t[njA * 3 + 0]; ntA1 = t[njA * 3 + 1]; ntA2 = t[njA * 3 + 2];
            ntB0 = t[njB * 3 + 0]; ntB1 = t[njB * 3 + 1]; ntB2 = t[njB * 3 + 2];
            nvA0 = v[njA * 2 + 0];
            nvB0 = v[njB * 2 + 0];
        }

        // ---- process pair (A, B): two independent chains for ILP ----
        const int bA = jA / NJ, jjA = jA - bA * NJ;
        const int bB = jB / NJ, jjB = jB - bB * NJ;

        const int xiA = (int)truncf(tA0 * (float)COL);
        const int yiA = (int)truncf(tA1 * (float)COL);
        const int xiB = (int)truncf(tB0 * (float)COL);
        const int yiB = (int)truncf(tB1 * (float)COL);
        const bool maskA = (vA0 == 1) && (xiA >= 0) && (xiA <= COL - 1) && (yiA >= 0) && (yiA <= COL - 1);
        const bool maskB = (vB0 == 1) && (xiB >= 0) && (xiB <= COL - 1) && (yiB >= 0) && (yiB <= COL - 1);
        const int xcA = min(max(xiA, 0), COL - 1), ycA = min(max(yiA, 0), COL - 1);
        const int xcB = min(max(xiB, 0), COL - 1), ycB = min(max(yiB, 0), COL - 1);

        const float hvA[4] = {hA.x, hA.y, hA.z, hA.w};
        const float hvB[4] = {hB.x, hB.y, hB.z, hB.w};

        // local argmax (first occurrence) for both joints
        float lvA = -INFINITY, lvB = -INFINITY;
        int   lqA = 0, lqB = 0;
        if (act) {
            #pragma unroll
            for (int k = 0; k < 4; ++k) {
                if (hvA[k] > lvA) { lvA = hvA[k]; lqA = q0 + k; }
                if (hvB[k] > lvB) { lvB = hvB[k]; lqB = q0 + k; }
            }
        }

        // d1 accumulation, joint A
        if (maskA) {
            const float mn  = sColMin[ycA] * sColMin[xcA];
            const float mx  = sColMax[ycA] * sColMax[xcA];
            const float inv = 1.0f / (mx - mn);
            if (act) {
                #pragma unroll
                for (int k = 0; k < 4; ++k) {
                    float ttv = (sM[rk[k] * COL + ycA] * sM[ck[k] * COL + xcA] - mn) * inv;
                    float d = hvA[k] - ttv;
                    accD += d * d;
                }
            }
        } else if (act) {
            #pragma unroll
            for (int k = 0; k < 4; ++k)
                accD += hvA[k] * hvA[k];
        }
        // d1 accumulation, joint B
        if (maskB) {
            const float mn  = sColMin[ycB] * sColMin[xcB];
            const float mx  = sColMax[ycB] * sColMax[xcB];
            const float inv = 1.0f / (mx - mn);
            if (act) {
                #pragma unroll
                for (int k = 0; k < 4; ++k) {
                    float ttv = (sM[rk[k] * COL + ycB] * sM[ck[k] * COL + xcB] - mn) * inv;
                    float d = hvB[k] - ttv;
                    accD += d * d;
                }
            }
        } else if (act) {
            #pragma unroll
            for (int k = 0; k < 4; ++k)
                accD += hvB[k] * hvB[k];
        }

        // wave argmax: two interleaved value-only butterflies (independent chains)
        float wA = lvA, wB = lvB;
        #pragma unroll
        for (int off = 1; off < 64; off <<= 1) {
            wA = fmaxf(wA, __shfl_xor(wA, off, 64));
            wB = fmaxf(wB, __shfl_xor(wB, off, 64));
        }
        unsigned long long mbA = __ballot(act && (lvA == wA));
        unsigned long long mbB = __ballot(act && (lvB == wB));
        const int srcA = (int)(__ffsll((long long)mbA) - 1);
        const int srcB = (int)(__ffsll((long long)mbB) - 1);
        const int bestiA = __shfl(lqA, srcA, 64);
        const int bestiB = __shfl(lqB, srcB, 64);

        // ---- consume DEFERRED d2 from previous pair (o loads issued last iter) ----
        if (lane < 3) {
            const float dA = povA + pcA;
            const float dB = povB + pcB;
            accD += dA * dA + dB * dB;
        }

        // ---- issue this pair's scattered o loads; consume next iteration ----
        const int byA = bestiA / COL, bxA = bestiA - (bestiA / COL) * COL;
        const int byB = bestiB / COL, bxB = bestiB - (bestiB / COL) * COL;
        if (lane < 3) {
            const size_t obA = (((size_t)bA * (3 * NJ) + jjA + lane * NJ) * COL + byA) * COL + bxA;
            const size_t obB = (((size_t)bB * (3 * NJ) + jjB + lane * NJ) * COL + byB) * COL + bxB;
            povA = o[obA];
            povB = o[obB];
            pcA = (lane == 0) ? ((float)bxA * scale - tA0)
                : (lane == 1) ? ((float)byA * scale - tA1)
                : (-tA2);
            pcB = (lane == 0) ? ((float)bxB * scale - tB0)
                : (lane == 1) ? ((float)byB * scale - tB1)
                : (-tB2);
        }

        // rotate pipeline registers
        jA += 2 * W; jB += 2 * W;
        hA = nA; hB = nB;
        tA0 = ntA0; tA1 = ntA1; tA2 = ntA2;
        tB0 = ntB0; tB1 = ntB1; tB2 = ntB2;
        vA0 = nvA0; vB0 = nvB0;
    }

    // ---- final deferred d2 (last pair) ----
    if (lane < 3) {
        const float dA = povA + pcA;
        const float dB = povB + pcB;
        accD += dA * dA + dB * dB;
    }

    // wave sum reduction
    #pragma unroll
    for (int off = 32; off > 0; off >>= 1)
        accD += __shfl_down(accD, off, 64);
    if (lane == 0) sWaveSum[wave_in_blk] = accD;
    __syncthreads();
    if (tid == 0) {
        float s = 0.0f;
        #pragma unroll
        for (int w = 0; w < THREADS / 64; ++w) s += sWaveSum[w];
        atomicAdd(out, s * (1.0f / (float)NJ));
    }
}

extern "C" void kernel_launch(void* const* d_in, const int* in_sizes, int n_in,
                              void* d_out, int out_size, void* d_ws, size_t ws_size,
                              hipStream_t stream) {
    const float* o = (const float*)d_in[0];
    const float* h = (const float*)d_in[1];
    const float* t = (const float*)d_in[2];
    const int*   v = (const int*)d_in[3];
    float* out = (float*)d_out;

    hipMemsetAsync(d_out, 0, sizeof(float), stream);
    msq3d_kernel<<<BLOCKS, THREADS, 0, stream>>>(o, h, t, v, out);
}

// Round 3
// 320.388 us; speedup vs baseline: 1.0162x; 1.0162x over previous
//
#include <hip/hip_runtime.h>
#include <math.h>

#define COL 14
#define NJ 23
#define BATCH 4096
#define NJOINT (BATCH * NJ)              // 94208
#define RADIUS 4
#define THREADS 256
#define BLOCKS 1472                      // 5888 waves = 256*23; 94208/5888 = 16 joints/wave EXACTLY
#define WAVES_TOTAL (BLOCKS * (THREADS / 64))   // 5888 = 256 * NJ  (j is wave-invariant!)
#define JPW (NJOINT / WAVES_TOTAL)       // 16

// full 64-lane max via DPP (VALU pipe) + one ds_swizzle + 2 readlane; result wave-uniform
__device__ __forceinline__ float wave_max_f32(float x) {
    int xi;
    xi = __builtin_amdgcn_update_dpp(__float_as_int(x), __float_as_int(x), 0xB1, 0xF, 0xF, true);  // lane^1
    x = fmaxf(x, __int_as_float(xi));
    xi = __builtin_amdgcn_update_dpp(__float_as_int(x), __float_as_int(x), 0x4E, 0xF, 0xF, true);  // lane^2
    x = fmaxf(x, __int_as_float(xi));
    xi = __builtin_amdgcn_update_dpp(__float_as_int(x), __float_as_int(x), 0x141, 0xF, 0xF, true); // half-mirror (8)
    x = fmaxf(x, __int_as_float(xi));
    xi = __builtin_amdgcn_update_dpp(__float_as_int(x), __float_as_int(x), 0x140, 0xF, 0xF, true); // mirror (16)
    x = fmaxf(x, __int_as_float(xi));
    xi = __builtin_amdgcn_ds_swizzle(__float_as_int(x), 0x401F);                                    // lane^16
    x = fmaxf(x, __int_as_float(xi));
    const float a = __int_as_float(__builtin_amdgcn_readlane(__float_as_int(x), 0));
    const float b = __int_as_float(__builtin_amdgcn_readlane(__float_as_int(x), 32));
    return fmaxf(a, b);
}

__global__ __launch_bounds__(THREADS, 6) void msq3d_kernel(
    const float* __restrict__ o,
    const float* __restrict__ h,
    const float* __restrict__ t,
    const int*   __restrict__ v,
    float* __restrict__ out)
{
    __shared__ float sM[COL * COL];         // M[row*COL + col]
    __shared__ float sColMin[COL], sColMax[COL];
    __shared__ float sWaveSum[THREADS / 64];

    const int tid = threadIdx.x;

    // ---- build Gaussian matrix M once per block (matches scipy reflect) ----
    if (tid < COL * COL) {
        double wd[2 * RADIUS + 1];
        double wsum = 0.0;
        #pragma unroll
        for (int k = 0; k <= 2 * RADIUS; ++k) {
            double xx = (double)(k - RADIUS);
            wd[k] = exp(-0.5 * xx * xx);
            wsum += wd[k];
        }
        const int outr = tid / COL, ic = tid % COL;
        float acc = 0.0f;
        #pragma unroll
        for (int k = -RADIUS; k <= RADIUS; ++k) {
            int ii = (outr + k) % (2 * COL);
            if (ii < 0) ii += 2 * COL;
            if (ii >= COL) ii = 2 * COL - 1 - ii;
            if (ii == ic) acc += (float)(wd[k + RADIUS] / wsum);
        }
        sM[outr * COL + ic] = acc;
    }
    __syncthreads();
    if (tid < COL) {
        float mn = sM[tid], mx = mn;
        for (int r = 1; r < COL; ++r) {
            float x = sM[r * COL + tid];
            mn = fminf(mn, x);
            mx = fmaxf(mx, x);
        }
        sColMin[tid] = mn;
        sColMax[tid] = mx;
    }
    __syncthreads();

    const int lane = tid & 63;
    const int wave_in_blk = tid >> 6;
    const int gwave = blockIdx.x * (THREADS / 64) + wave_in_blk;
    const float scale = 1.0f / (float)COL;

    // per-lane static geometry: lane handles elements q0..q0+3 of each 196-elem map
    const bool act = (lane < 49);           // 49 * 4 = 196
    const int q0 = lane * 4;
    int rk[4], ck[4];
    #pragma unroll
    for (int k = 0; k < 4; ++k) {
        int q = q0 + k;
        if (q > COL * COL - 1) q = COL * COL - 1;
        rk[k] = q / COL;
        ck[k] = q - rk[k] * COL;
    }

    // WAVES_TOTAL = 256*NJ  =>  successive joints of a wave share j; b += 256
    const int b0 = gwave / NJ;              // one division, outside the loop
    const int j0 = gwave - b0 * NJ;

    // walking pointers (all strides compile-time constants)
    const float4* hp = (const float4*)(h + (size_t)gwave * (COL * COL)) + lane;
    const float*  tp = t + (size_t)gwave * 3;
    const int*    vp = v + (size_t)gwave * 2;
    const size_t  HSTRIDE = (size_t)WAVES_TOTAL * (COL * COL) / 4;   // in float4
    const size_t  OSTRIDE = (size_t)256 * (3 * NJ) * (COL * COL);    // b += 256 per iter
    // o element base for this lane's component (lane 0->x, 1->y, 2->z), excluding by*COL+bx
    size_t obase = ((size_t)b0 * (3 * NJ) + j0 + (size_t)(lane < 3 ? lane : 0) * NJ) * (COL * COL);

    float accD = 0.0f;   // d1 partial on all lanes; d2 folded in on lanes 0..2

    // ---- prologue: load joint 0 ----
    float4 hv4 = make_float4(0.f, 0.f, 0.f, 0.f);
    if (act) hv4 = *hp;
    hp += HSTRIDE;
    float t0 = tp[0], t1 = tp[1], t2 = tp[2];
    int   v0 = vp[0];
    tp += (size_t)WAVES_TOTAL * 3;
    vp += (size_t)WAVES_TOTAL * 2;

    // deferred d2 state (o-load result consumed one iteration later; 0 on iter 0)
    float pov = 0.f, pc = 0.f;

    #pragma unroll 1
    for (int i = 0; i < JPW; ++i) {
        // ---- issue next joint's loads before touching this joint's data ----
        float4 nh4 = make_float4(0.f, 0.f, 0.f, 0.f);
        float nt0 = 0.f, nt1 = 0.f, nt2 = 0.f;
        int   nv0 = 0;
        if (i + 1 < JPW) {
            if (act) nh4 = *hp;
            nt0 = tp[0]; nt1 = tp[1]; nt2 = tp[2];
            nv0 = vp[0];
        }
        hp += HSTRIDE;
        tp += (size_t)WAVES_TOTAL * 3;
        vp += (size_t)WAVES_TOTAL * 2;

        // ---- process current joint ----
        const int xi = (int)truncf(t0 * (float)COL);
        const int yi = (int)truncf(t1 * (float)COL);
        const bool mask = (v0 == 1) && (xi >= 0) && (xi <= COL - 1) && (yi >= 0) && (yi <= COL - 1);
        const int xc = min(max(xi, 0), COL - 1);
        const int yc = min(max(yi, 0), COL - 1);

        const float hv[4] = {hv4.x, hv4.y, hv4.z, hv4.w};

        // local argmax over this lane's 4 elements (first occurrence)
        float lv = -INFINITY;
        int   lq = 0;
        if (act) {
            #pragma unroll
            for (int k = 0; k < 4; ++k) {
                if (hv[k] > lv) { lv = hv[k]; lq = q0 + k; }
            }
        }

        // d1 accumulation
        if (mask) {
            const float mn  = sColMin[yc] * sColMin[xc];
            const float mx  = sColMax[yc] * sColMax[xc];
            const float inv = 1.0f / (mx - mn);
            if (act) {
                #pragma unroll
                for (int k = 0; k < 4; ++k) {
                    float ttv = (sM[rk[k] * COL + yc] * sM[ck[k] * COL + xc] - mn) * inv;
                    float d = hv[k] - ttv;
                    accD += d * d;
                }
            }
        } else if (act) {
            #pragma unroll
            for (int k = 0; k < 4; ++k)
                accD += hv[k] * hv[k];
        }

        // wave argmax: DPP max (VALU pipe), ballot picks lowest lane (== first occurrence)
        const float wmax = wave_max_f32(lv);
        unsigned long long mb = __ballot(act && (lv == wmax));
        const int src = (int)(__ffsll((long long)mb) - 1);
        const int besti = __builtin_amdgcn_readlane(lq, src);

        // ---- consume DEFERRED d2 from previous joint (adds 0 on iter 0) ----
        if (lane < 3) {
            const float d = pov + pc;
            accD += d * d;
        }

        // ---- issue this joint's scattered o load; consume next iteration ----
        const int by = besti / COL;
        const int bx = besti - by * COL;
        if (lane < 3) {
            pov = o[obase + (size_t)(by * COL + bx)];
            pc = (lane == 0) ? ((float)bx * scale - t0)
               : (lane == 1) ? ((float)by * scale - t1)
               : (-t2);
        }
        obase += OSTRIDE;

        // rotate pipeline registers
        hv4 = nh4;
        t0 = nt0; t1 = nt1; t2 = nt2; v0 = nv0;
    }

    // ---- final deferred d2 (last joint) ----
    if (lane < 3) {
        const float d = pov + pc;
        accD += d * d;
    }

    // wave sum reduction
    #pragma unroll
    for (int off = 32; off > 0; off >>= 1)
        accD += __shfl_down(accD, off, 64);
    if (lane == 0) sWaveSum[wave_in_blk] = accD;
    __syncthreads();
    if (tid == 0) {
        float s = 0.0f;
        #pragma unroll
        for (int w = 0; w < THREADS / 64; ++w) s += sWaveSum[w];
        atomicAdd(out, s * (1.0f / (float)NJ));
    }
}

extern "C" void kernel_launch(void* const* d_in, const int* in_sizes, int n_in,
                              void* d_out, int out_size, void* d_ws, size_t ws_size,
                              hipStream_t stream) {
    const float* o = (const float*)d_in[0];
    const float* h = (const float*)d_in[1];
    const float* t = (const float*)d_in[2];
    const int*   v = (const int*)d_in[3];
    float* out = (float*)d_out;

    hipMemsetAsync(d_out, 0, sizeof(float), stream);
    msq3d_kernel<<<BLOCKS, THREADS, 0, stream>>>(o, h, t, v, out);
}

// Round 4
// 319.034 us; speedup vs baseline: 1.0205x; 1.0042x over previous
//
#include <hip/hip_runtime.h>
#include <math.h>

#define COL 14
#define NJ 23
#define BATCH 4096
#define NJOINT (BATCH * NJ)              // 94208
#define RADIUS 4
#define THREADS 256
#define BLOCKS 1472                      // 5888 waves = 256*23; 94208/5888 = 16 joints/wave EXACTLY
#define WAVES_TOTAL (BLOCKS * (THREADS / 64))   // 5888 = 256 * NJ  (j is wave-invariant)
#define JPW (NJOINT / WAVES_TOTAL)       // 16

// full 64-lane max via DPP (VALU pipe) + one ds_swizzle + 2 readlane; result wave-uniform
__device__ __forceinline__ float wave_max_f32(float x) {
    int xi;
    xi = __builtin_amdgcn_update_dpp(__float_as_int(x), __float_as_int(x), 0xB1, 0xF, 0xF, true);  // lane^1
    x = fmaxf(x, __int_as_float(xi));
    xi = __builtin_amdgcn_update_dpp(__float_as_int(x), __float_as_int(x), 0x4E, 0xF, 0xF, true);  // lane^2
    x = fmaxf(x, __int_as_float(xi));
    xi = __builtin_amdgcn_update_dpp(__float_as_int(x), __float_as_int(x), 0x141, 0xF, 0xF, true); // row half-mirror
    x = fmaxf(x, __int_as_float(xi));
    xi = __builtin_amdgcn_update_dpp(__float_as_int(x), __float_as_int(x), 0x140, 0xF, 0xF, true); // row mirror
    x = fmaxf(x, __int_as_float(xi));
    xi = __builtin_amdgcn_ds_swizzle(__float_as_int(x), 0x401F);                                    // lane^16
    x = fmaxf(x, __int_as_float(xi));
    const float a = __int_as_float(__builtin_amdgcn_readlane(__float_as_int(x), 0));
    const float b = __int_as_float(__builtin_amdgcn_readlane(__float_as_int(x), 32));
    return fmaxf(a, b);
}

__global__ __launch_bounds__(THREADS, 6) void msq3d_kernel(
    const float* __restrict__ o,
    const float* __restrict__ h,
    const float* __restrict__ t,
    const int*   __restrict__ v,
    float* __restrict__ out)
{
    __shared__ float sM[COL * COL];         // M[row*COL + col]
    __shared__ float sColMin[COL], sColMax[COL];
    __shared__ float sWaveSum[THREADS / 64];

    const int tid = threadIdx.x;

    // ---- build Gaussian matrix M once per block (matches scipy reflect) ----
    if (tid < COL * COL) {
        double wd[2 * RADIUS + 1];
        double wsum = 0.0;
        #pragma unroll
        for (int k = 0; k <= 2 * RADIUS; ++k) {
            double xx = (double)(k - RADIUS);
            wd[k] = exp(-0.5 * xx * xx);
            wsum += wd[k];
        }
        const int outr = tid / COL, ic = tid % COL;
        float acc = 0.0f;
        #pragma unroll
        for (int k = -RADIUS; k <= RADIUS; ++k) {
            int ii = (outr + k) % (2 * COL);
            if (ii < 0) ii += 2 * COL;
            if (ii >= COL) ii = 2 * COL - 1 - ii;
            if (ii == ic) acc += (float)(wd[k + RADIUS] / wsum);
        }
        sM[outr * COL + ic] = acc;
    }
    __syncthreads();
    if (tid < COL) {
        float mn = sM[tid], mx = mn;
        for (int r = 1; r < COL; ++r) {
            float x = sM[r * COL + tid];
            mn = fminf(mn, x);
            mx = fmaxf(mx, x);
        }
        sColMin[tid] = mn;
        sColMax[tid] = mx;
    }
    __syncthreads();

    const int lane = tid & 63;
    const int wave_in_blk = tid >> 6;
    const int gwave = blockIdx.x * (THREADS / 64) + wave_in_blk;
    const float scale = 1.0f / (float)COL;

    // per-lane static geometry: lane handles elements q0..q0+3 of each 196-elem map
    const bool act = (lane < 49);           // 49 * 4 = 196
    const int laneC = min(lane, 48);        // clamped lane for UNCONDITIONAL loads (no exec-mask dance;
                                            // lanes 49-63 re-read lane 48's cache line: zero extra traffic)
    const int q0 = lane * 4;
    int rk[4], ck[4];
    #pragma unroll
    for (int k = 0; k < 4; ++k) {
        int q = q0 + k;
        if (q > COL * COL - 1) q = COL * COL - 1;
        rk[k] = q / COL;
        ck[k] = q - rk[k] * COL;
    }

    // WAVES_TOTAL = 256*NJ  =>  successive joints of a wave share j; b += 256
    const int b0 = gwave / NJ;              // one division, outside the loop
    const int j0 = gwave - b0 * NJ;

    // walking pointers (all strides compile-time constants)
    const float4* hp = (const float4*)(h + (size_t)gwave * (COL * COL)) + laneC;
    const float*  tp = t + (size_t)gwave * 3;
    const int*    vp = v + (size_t)gwave * 2;
    const size_t  HSTRIDE = (size_t)WAVES_TOTAL * (COL * COL) / 4;   // in float4
    const size_t  OSTRIDE = (size_t)256 * (3 * NJ) * (COL * COL);    // b += 256 per iter
    size_t obase = ((size_t)b0 * (3 * NJ) + j0 + (size_t)(lane < 3 ? lane : 0) * NJ) * (COL * COL);

    float accD = 0.0f;   // d1 partial on all lanes; d2 folded in on lanes 0..2

    // ---- prologue: DEPTH-2 h prefetch (raises per-CU bytes-in-flight past Little's-law threshold),
    //      depth-1 t/v prefetch ----
    float4 hc = hp[0];                       // h for iter 0
    float4 h1 = hp[HSTRIDE];                 // h for iter 1
    hp += 2 * HSTRIDE;                       // next issue target: iter 2
    float t0 = tp[0], t1 = tp[1], t2 = tp[2];
    int   v0 = vp[0];
    tp += (size_t)WAVES_TOTAL * 3;
    vp += (size_t)WAVES_TOTAL * 2;

    // deferred d2 state (o-load result consumed one iteration later; adds 0 on iter 0)
    float pov = 0.f, pc = 0.f;

    #pragma unroll 1
    for (int i = 0; i < JPW; ++i) {
        // ---- issue iter i+2's h load and iter i+1's t/v loads ----
        float4 h2 = make_float4(0.f, 0.f, 0.f, 0.f);
        if (i + 2 < JPW) h2 = *hp;           // wave-uniform branch
        hp += HSTRIDE;
        float nt0 = 0.f, nt1 = 0.f, nt2 = 0.f;
        int   nv0 = 0;
        if (i + 1 < JPW) {
            nt0 = tp[0]; nt1 = tp[1]; nt2 = tp[2];
            nv0 = vp[0];
        }
        tp += (size_t)WAVES_TOTAL * 3;
        vp += (size_t)WAVES_TOTAL * 2;

        // ---- process current joint ----
        const int xi = (int)truncf(t0 * (float)COL);
        const int yi = (int)truncf(t1 * (float)COL);
        const bool mask = (v0 == 1) && (xi >= 0) && (xi <= COL - 1) && (yi >= 0) && (yi <= COL - 1);
        const int xc = min(max(xi, 0), COL - 1);
        const int yc = min(max(yi, 0), COL - 1);

        const float hv[4] = {hc.x, hc.y, hc.z, hc.w};

        // local argmax over this lane's 4 elements (first occurrence)
        float lv = -INFINITY;
        int   lq = 0;
        if (act) {
            #pragma unroll
            for (int k = 0; k < 4; ++k) {
                if (hv[k] > lv) { lv = hv[k]; lq = q0 + k; }
            }
        }

        // d1 accumulation
        if (mask) {
            const float mn  = sColMin[yc] * sColMin[xc];
            const float mx  = sColMax[yc] * sColMax[xc];
            const float inv = 1.0f / (mx - mn);
            if (act) {
                #pragma unroll
                for (int k = 0; k < 4; ++k) {
                    float ttv = (sM[rk[k] * COL + yc] * sM[ck[k] * COL + xc] - mn) * inv;
                    float d = hv[k] - ttv;
                    accD += d * d;
                }
            }
        } else if (act) {
            #pragma unroll
            for (int k = 0; k < 4; ++k)
                accD += hv[k] * hv[k];
        }

        // wave argmax: DPP max (VALU pipe), ballot picks lowest lane (== first occurrence)
        const float wmax = wave_max_f32(lv);
        unsigned long long mb = __ballot(act && (lv == wmax));
        const int src = (int)(__ffsll((long long)mb) - 1);
        const int besti = __builtin_amdgcn_readlane(lq, src);

        // ---- consume DEFERRED d2 from previous joint (adds 0 on iter 0) ----
        if (lane < 3) {
            const float d = pov + pc;
            accD += d * d;
        }

        // ---- issue this joint's scattered o load; consume next iteration ----
        const int by = besti / COL;
        const int bx = besti - by * COL;
        if (lane < 3) {
            pov = o[obase + (size_t)(by * COL + bx)];
            pc = (lane == 0) ? ((float)bx * scale - t0)
               : (lane == 1) ? ((float)by * scale - t1)
               : (-t2);
        }
        obase += OSTRIDE;

        // rotate pipeline registers
        hc = h1; h1 = h2;
        t0 = nt0; t1 = nt1; t2 = nt2; v0 = nv0;
    }

    // ---- final deferred d2 (last joint) ----
    if (lane < 3) {
        const float d = pov + pc;
        accD += d * d;
    }

    // wave sum reduction
    #pragma unroll
    for (int off = 32; off > 0; off >>= 1)
        accD += __shfl_down(accD, off, 64);
    if (lane == 0) sWaveSum[wave_in_blk] = accD;
    __syncthreads();
    if (tid == 0) {
        float s = 0.0f;
        #pragma unroll
        for (int w = 0; w < THREADS / 64; ++w) s += sWaveSum[w];
        atomicAdd(out, s * (1.0f / (float)NJ));
    }
}

extern "C" void kernel_launch(void* const* d_in, const int* in_sizes, int n_in,
                              void* d_out, int out_size, void* d_ws, size_t ws_size,
                              hipStream_t stream) {
    const float* o = (const float*)d_in[0];
    const float* h = (const float*)d_in[1];
    const float* t = (const float*)d_in[2];
    const int*   v = (const int*)d_in[3];
    float* out = (float*)d_out;

    hipMemsetAsync(d_out, 0, sizeof(float), stream);
    msq3d_kernel<<<BLOCKS, THREADS, 0, stream>>>(o, h, t, v, out);
}